// Round 4
// baseline (227.520 us; speedup 1.0000x reference)
//
#include <hip/hip_runtime.h>
#include <math.h>

#define NLEV 5
#define TOPKK 1000
#define NCLS 16
#define NPART 16                 // cand partitions (by chunk id)
#define HP 4                     // histogram partial copies
#define PART_CAP 256
#define CAND_TOT 2048
#define NCHUNK 3069u             // 785664 / 256
#define HISTSZ (NLEV * 256)

// level boundaries; sizes: 589824, 147456, 36864, 9216, 2304
// ALL boundaries are multiples of 256 -> a 256-thread chunk never straddles
__device__ __forceinline__ int find_level(unsigned i, unsigned& loc) {
    if (i < 589824u) { loc = i;            return 0; }
    if (i < 737280u) { loc = i - 589824u;  return 1; }
    if (i < 774144u) { loc = i - 737280u;  return 2; }
    if (i < 783360u) { loc = i - 774144u;  return 3; }
    loc = i - 783360u; return 4;
}

struct Ptrs {
    const float* anc[NLEV];
    const float* cls[NLEV];
    const float* reg[NLEV];
};

// order-preserving float32 -> uint32 (larger uint == larger float)
__device__ __forceinline__ unsigned f2key(float f) {
    unsigned u = __float_as_uint(f);
    return (u & 0x80000000u) ? ~u : (u | 0x80000000u);
}

__device__ __forceinline__ float max4(float4 v) {
    return fmaxf(fmaxf(v.x, v.y), fmaxf(v.z, v.w));
}

// ---- software grid barrier v2 -------------------------------------------
// Round-2's barrier cost ~100us each: 1024 ACQ_REL arrivals + acquire-poll
// storm on ONE line. v2: relaxed arrivals (one release/acquire fence per
// leader), 9 heavy ops total, and hierarchical polling (8 blocks poll gen,
// everyone else polls 8 relay lines -> ~100x less pressure per line).
// Layout (u32 idx, hot words on separate 64B lines):
//   sub[g]=bar[g*16] g=0..7 ; master=bar[128] ; gen=bar[144] ;
//   relay[g]=bar[160+g*16]  (total 288 u32 = 1152 B)
// Generation-relative + counters self-restore to 0 -> rocprof-replay-safe
// (verified property of the round-2 design, which was correct, just slow).
__device__ __forceinline__ void gridbar(unsigned* bar, unsigned nb) {
    __syncthreads();
    if (threadIdx.x == 0) {
        __builtin_amdgcn_fence(__ATOMIC_RELEASE, "agent");
        unsigned grp = blockIdx.x & 7u;
        unsigned gsz = (nb + 7u - grp) / 8u;               // exact group size
        unsigned g0 = __hip_atomic_load(bar + 144, __ATOMIC_RELAXED,
                                        __HIP_MEMORY_SCOPE_AGENT);
        unsigned a = __hip_atomic_fetch_add(bar + grp * 16u, 1u,
                        __ATOMIC_RELAXED, __HIP_MEMORY_SCOPE_AGENT);
        if (a == gsz - 1u) {                               // last of my group
            __hip_atomic_store(bar + grp * 16u, 0u,
                               __ATOMIC_RELAXED, __HIP_MEMORY_SCOPE_AGENT);
            unsigned m = __hip_atomic_fetch_add(bar + 128, 1u,
                            __ATOMIC_ACQ_REL, __HIP_MEMORY_SCOPE_AGENT);
            if (m == 7u) {                                 // last group overall
                __hip_atomic_store(bar + 128, 0u,
                                   __ATOMIC_RELAXED, __HIP_MEMORY_SCOPE_AGENT);
                __hip_atomic_fetch_add(bar + 144, 1u,
                                       __ATOMIC_ACQ_REL, __HIP_MEMORY_SCOPE_AGENT);
            }
        }
        if (blockIdx.x < 8u) {                             // relay duty
            while (__hip_atomic_load(bar + 144, __ATOMIC_RELAXED,
                                     __HIP_MEMORY_SCOPE_AGENT) == g0)
                __builtin_amdgcn_s_sleep(8);
            __hip_atomic_store(bar + 160u + blockIdx.x * 16u, g0 + 1u,
                               __ATOMIC_RELAXED, __HIP_MEMORY_SCOPE_AGENT);
        } else {
            while ((int)(__hip_atomic_load(bar + 160u + grp * 16u,
                         __ATOMIC_RELAXED, __HIP_MEMORY_SCOPE_AGENT)
                         - (g0 + 1u)) < 0)
                __builtin_amdgcn_s_sleep(16);
        }
        __builtin_amdgcn_fence(__ATOMIC_ACQUIRE, "agent");
    }
    __syncthreads();
}

// suffix-scan over 256 bins (bin == threadIdx), find bin holding the rem-th
// largest. aux[0] <- bin ; aux[1] <- remainder. (verbatim verified core)
__device__ void suffix_select(unsigned c, unsigned rem, unsigned* s, unsigned* aux) {
    int t = threadIdx.x, r = 255 - t;
    s[r] = c;
    __syncthreads();
    for (int d = 1; d < 256; d <<= 1) {
        unsigned v = (r >= d) ? s[r - d] : 0u;
        __syncthreads();
        s[r] += v;
        __syncthreads();
    }
    unsigned incl = s[r], above = incl - c;
    if (above < rem && rem <= incl) {
        aux[0] = (unsigned)t;
        aux[1] = rem - above;
    }
    __syncthreads();
}

// One persistent kernel, 3 grid barriers. The two radix selects are
// recomputed per block from the completed global histograms (cheap at 512
// blocks) -> no barrier needed around a 5-block select phase.
__global__ __launch_bounds__(256, 2) void k_fused(Ptrs p, unsigned* keys,
        unsigned* histA, unsigned* histB, unsigned* cnt, unsigned* bar,
        unsigned long long* cand, float* out, unsigned nb) {
    __shared__ union ShU {
        unsigned long long lbuf[CAND_TOT];   // 16 KB (rank phase)
        unsigned h[NLEV * 256];              // block-level hist accumulator
        unsigned s[256];                     // suffix-scan space
    } sh;
    __shared__ unsigned aux[33];
    __shared__ unsigned pfs[NLEV], rems[NLEV], ths[NLEV];

    const unsigned b = blockIdx.x;
    const int t = threadIdx.x;

    // ---- Phase A: keys -> global; block-level byte-1 hist, one flush ----
    #pragma unroll
    for (int j = 0; j < NLEV; j++) sh.h[j * 256 + t] = 0u;
    __syncthreads();
    for (unsigned c = b; c < NCHUNK; c += nb) {
        unsigned loc; int l = find_level(c * 256u + (unsigned)t, loc);
        const float4* cp = (const float4*)(p.cls[l]) + (size_t)loc * 4;
        float4 v0 = cp[0], v1 = cp[1], v2 = cp[2], v3 = cp[3];
        float m = fmaxf(fmaxf(max4(v0), max4(v1)), fmaxf(max4(v2), max4(v3)));
        unsigned k = f2key(m);
        keys[c * 256u + (unsigned)t] = k;
        atomicAdd(&sh.h[(unsigned)l * 256u + (k >> 24)], 1u);
    }
    __syncthreads();
    {
        unsigned part = b & (HP - 1u);
        #pragma unroll
        for (int j = 0; j < NLEV; j++) {
            unsigned v = sh.h[j * 256 + t];
            if (v) atomicAdd(&histA[part * HISTSZ + (unsigned)j * 256u + (unsigned)t], v);
        }
    }
    gridbar(bar, nb);

    // ---- Select byte-1 per level (redundant per block; histA complete) ----
    for (int l = 0; l < NLEV; l++) {
        unsigned c = 0;
        #pragma unroll
        for (int pp = 0; pp < HP; pp++)
            c += histA[pp * HISTSZ + l * 256 + t];
        suffix_select(c, TOPKK, sh.s, aux);
        if (t == 0) { pfs[l] = aux[0]; rems[l] = aux[1]; }
        __syncthreads();
    }

    // ---- Phase C: byte-2 hist of keys matching byte-1 prefix ----
    #pragma unroll
    for (int j = 0; j < NLEV; j++) sh.h[j * 256 + t] = 0u;
    __syncthreads();
    for (unsigned c = b; c < NCHUNK; c += nb) {
        unsigned loc; int l = find_level(c * 256u + (unsigned)t, loc);
        unsigned k = keys[c * 256u + (unsigned)t];
        if ((k >> 24) == pfs[l])
            atomicAdd(&sh.h[(unsigned)l * 256u + ((k >> 16) & 0xFFu)], 1u);
    }
    __syncthreads();
    {
        unsigned part = b & (HP - 1u);
        #pragma unroll
        for (int j = 0; j < NLEV; j++) {
            unsigned v = sh.h[j * 256 + t];
            if (v) atomicAdd(&histB[part * HISTSZ + (unsigned)j * 256u + (unsigned)t], v);
        }
    }
    gridbar(bar, nb);

    // ---- Select byte-2 per level -> 16-bit threshold (redundant) ----
    for (int l = 0; l < NLEV; l++) {
        unsigned c = 0;
        #pragma unroll
        for (int pp = 0; pp < HP; pp++)
            c += histB[pp * HISTSZ + l * 256 + t];
        suffix_select(c, rems[l], sh.s, aux);
        if (t == 0) ths[l] = (pfs[l] << 24) | (aux[0] << 16);
        __syncthreads();
    }

    // ---- Phase E: compact candidates ----
    for (unsigned c = b; c < NCHUNK; c += nb) {
        unsigned loc; int l = find_level(c * 256u + (unsigned)t, loc);
        unsigned k = keys[c * 256u + (unsigned)t];
        if (k >= ths[l]) {
            unsigned part = c & (NPART - 1u);
            unsigned slot = atomicAdd(&cnt[l * NPART + part], 1u);
            if (slot < PART_CAP)
                cand[((size_t)(l * NPART + part)) * PART_CAP + slot] =
                    ((unsigned long long)k << 32) | (unsigned)(~loc);
        }
    }
    gridbar(bar, nb);

    // ---- Phase F: rank-by-counting + emit (blocks 0..39, 8 per level) ----
    if (b >= (unsigned)(NLEV * 8)) return;
    const float MAXD = 4.135166556742356f;   // log(1000/16)
    int l = (int)(b >> 3);
    unsigned sl = b & 7u;

    if (t < NPART) {
        unsigned cc = cnt[l * NPART + t];
        aux[t] = (cc > PART_CAP) ? PART_CAP : cc;
    }
    __syncthreads();
    if (t == 0) {
        unsigned o = 0;
        for (int pp = 0; pp < NPART; pp++) { aux[16 + pp] = o; o += aux[pp]; }
        aux[32] = (o > CAND_TOT) ? CAND_TOT : o;
    }
    __syncthreads();
    unsigned n = aux[32];
    for (int pp = 0; pp < NPART; pp++) {
        unsigned cc = aux[pp], o = aux[16 + pp];
        for (unsigned e = (unsigned)t; e < cc; e += 256u) {
            unsigned dst = o + e;
            if (dst < CAND_TOT)
                sh.lbuf[dst] = cand[((size_t)(l * NPART + pp)) * PART_CAP + e];
        }
    }
    __syncthreads();

    unsigned j = sl * 256u + (unsigned)t;
    if (j >= n) return;
    unsigned long long my = sh.lbuf[j];
    unsigned rank = 0;
    #pragma unroll 8
    for (unsigned q = 0; q < n; q++) rank += (sh.lbuf[q] > my) ? 1u : 0u;
    if (rank >= TOPKK) return;

    unsigned idx = ~((unsigned)(my & 0xFFFFFFFFull));
    float4 an = ((const float4*)p.anc[l])[idx];
    float4 dd = ((const float4*)p.reg[l])[(size_t)idx * 2];
    float w = an.z - an.x, h = an.w - an.y;
    float cx = an.x + 0.5f * w, cy = an.y + 0.5f * h;
    float pcx = cx + dd.x * w, pcy = cy + dd.y * h;
    float pw = w * expf(fminf(dd.z, MAXD));
    float ph = h * expf(fminf(dd.w, MAXD));
    float bx = pcx - 0.5f * pw, by = pcy - 0.5f * ph;
    float bz = pcx + 0.5f * pw, bw = pcy + 0.5f * ph;

    const float4* cp = (const float4*)(p.cls[l]) + (size_t)idx * 4;
    float sg[16];
    #pragma unroll
    for (int g = 0; g < 4; g++) {
        float4 v = cp[g];
        sg[4 * g + 0] = 1.0f / (1.0f + expf(-v.x));
        sg[4 * g + 1] = 1.0f / (1.0f + expf(-v.y));
        sg[4 * g + 2] = 1.0f / (1.0f + expf(-v.z));
        sg[4 * g + 3] = 1.0f / (1.0f + expf(-v.w));
    }
    // 16 rows of [bx,by,bz,bw,score,tag] == 24 float4s, 384B contiguous
    float4* q = (float4*)(out + (size_t)(l * TOPKK + rank) * (NCLS * 6));
    #pragma unroll
    for (int g = 0; g < 8; g++) {
        float ta = (float)(2 * g + 1), tb = (float)(2 * g + 2);
        q[3 * g + 0] = make_float4(bx, by, bz, bw);
        q[3 * g + 1] = make_float4(sg[2 * g], ta, bx, by);
        q[3 * g + 2] = make_float4(bz, bw, sg[2 * g + 1], tb);
    }
}

extern "C" void kernel_launch(void* const* d_in, const int* in_sizes, int n_in,
                              void* d_out, int out_size, void* d_ws, size_t ws_size,
                              hipStream_t stream) {
    (void)in_sizes; (void)n_in; (void)out_size; (void)ws_size;
    Ptrs p;
    for (int l = 0; l < NLEV; l++) {
        p.anc[l] = (const float*)d_in[3 * l + 0];
        p.cls[l] = (const float*)d_in[3 * l + 1];
        p.reg[l] = (const float*)d_in[3 * l + 2];
    }

    // Grid = runtime-guaranteed co-resident blocks (cached host queries).
    static unsigned s_nb = 0;
    if (s_nb == 0) {
        int bpcu = 0;
        if (hipOccupancyMaxActiveBlocksPerMultiprocessor(
                &bpcu, (const void*)k_fused, 256, 0) != hipSuccess || bpcu < 1)
            bpcu = 1;
        int dev = 0, ncu = 0;
        (void)hipGetDevice(&dev);
        if (hipDeviceGetAttribute(&ncu, hipDeviceAttributeMultiprocessorCount,
                                  dev) != hipSuccess || ncu < 1)
            ncu = 256;
        unsigned long long nb = (unsigned long long)bpcu * (unsigned long long)ncu;
        if (nb > 512ull) nb = 512ull;        // 2/CU: fewer barrier participants
        if (nb < 64ull) nb = 64ull;          // >= 40 needed for phase F
        s_nb = (unsigned)nb;
    }

    char* w = (char*)d_ws;
    // layout (bytes):
    //   histA : 0     .. 20480  \
    //   histB : 20480 .. 40960   } one contiguous memset (42432 B)
    //   cnt   : 40960 .. 41280   }
    //   bar   : 41280 .. 42432  /   (barrier state; design is replay-safe)
    //   keys  : 42432 .. 3185088    (written before read, no memset)
    //   cand  : 3185088 .. 3348928  (guarded by cnt, no memset)
    unsigned* histA = (unsigned*)w;
    unsigned* histB = (unsigned*)(w + 20480);
    unsigned* cnt   = (unsigned*)(w + 40960);
    unsigned* bar   = (unsigned*)(w + 41280);
    unsigned* keys  = (unsigned*)(w + 42432);
    unsigned long long* cand = (unsigned long long*)(w + 3185088);
    float* out = (float*)d_out;

    (void)hipMemsetAsync(w, 0, 42432, stream);
    k_fused<<<dim3(s_nb), dim3(256), 0, stream>>>(p, keys, histA, histB, cnt,
                                                  bar, cand, out, s_nb);
}

// Round 5
// 202.025 us; speedup vs baseline: 1.1262x; 1.1262x over previous
//
#include <hip/hip_runtime.h>
#include <math.h>

#define NLEV 5
#define TOPKK 1000
#define NCLS 16
#define NPART 16                 // cand partitions (by chunk id)
#define HP 4                     // histogram partial copies
#define PART_CAP 256
#define CAND_TOT 2048
#define NCHUNK 3069u             // 785664 / 256
#define CPB 6u                   // chunks per block: 512*6 = 3072 >= 3069
#define NB 512u                  // co-residency VERIFIED in round 4 (same config)
#define HISTSZ (NLEV * 256)

// chunk-index level boundaries: 2304, 2880, 3024, 3060 — ALL divisible by
// CPB=6, so every block's 6 chunks belong to ONE level (level-pure blocks).
__device__ __forceinline__ int lev_of_chunk(unsigned c) {
    if (c < 2304u) return 0;
    if (c < 2880u) return 1;
    if (c < 3024u) return 2;
    if (c < 3060u) return 3;
    return 4;
}
__device__ __forceinline__ unsigned lev_base(int l) {   // entry base per level
    unsigned b = 0u;
    if (l == 1) b = 589824u;
    if (l == 2) b = 737280u;
    if (l == 3) b = 774144u;
    if (l == 4) b = 783360u;
    return b;
}

struct Ptrs {
    const float* anc[NLEV];
    const float* cls[NLEV];
    const float* reg[NLEV];
};

// order-preserving float32 -> uint32 (larger uint == larger float)
__device__ __forceinline__ unsigned f2key(float f) {
    unsigned u = __float_as_uint(f);
    return (u & 0x80000000u) ? ~u : (u | 0x80000000u);
}

__device__ __forceinline__ float max4(float4 v) {
    return fmaxf(fmaxf(v.x, v.y), fmaxf(v.z, v.w));
}

// ---- one-shot grid barrier ----------------------------------------------
// Each barrier instance has its OWN counter set (no generation, no reset):
//   sub[g]  = base[g*16]        g = 0..15   (relaxed arrivals, 32/line)
//   master  = base[256]
//   relay[g]= base[512 + g*16]              (fan-out; waiters poll own line)
// Release fence before arrival is ~free here (nothing dirty in L2: keys are
// in registers; all shared state is written via device-scope atomics).
// Acquire fence after wait also kills cross-launch stale-L2 lines.
__device__ __forceinline__ void arrive_wait(unsigned* base, bool dowait) {
    __syncthreads();
    if (threadIdx.x == 0) {
        __builtin_amdgcn_fence(__ATOMIC_RELEASE, "agent");
        unsigned g = blockIdx.x & 15u;
        unsigned a = __hip_atomic_fetch_add(base + g * 16u, 1u,
                        __ATOMIC_RELAXED, __HIP_MEMORY_SCOPE_AGENT);
        if (a == NB / 16u - 1u) {                      // last of my line
            unsigned m = __hip_atomic_fetch_add(base + 256u, 1u,
                            __ATOMIC_RELAXED, __HIP_MEMORY_SCOPE_AGENT);
            if (m == 15u) {                            // last overall: fan out
                #pragma unroll
                for (unsigned r = 0; r < 16u; r++)
                    __hip_atomic_store(base + 512u + r * 16u, 1u,
                                       __ATOMIC_RELAXED, __HIP_MEMORY_SCOPE_AGENT);
            }
        }
        if (dowait) {
            while (!__hip_atomic_load(base + 512u + g * 16u,
                        __ATOMIC_RELAXED, __HIP_MEMORY_SCOPE_AGENT))
                __builtin_amdgcn_s_sleep(4);
            __builtin_amdgcn_fence(__ATOMIC_ACQUIRE, "agent");
        }
    }
    __syncthreads();
}

// suffix-select over 256 bins (bin == threadIdx) via wave shuffles: 2 syncs
// instead of 26. Finds bin holding the rem-th largest; aux[0]=bin,
// aux[1]=remainder within bin. Semantics identical to the verified scan.
__device__ __forceinline__ void sel256(unsigned c, unsigned rem,
                                       unsigned* wsum, unsigned* aux) {
    int t = threadIdx.x, lane = t & 63, wv = t >> 6;
    unsigned s = c;                          // suffix-sum over lanes >= mine
    #pragma unroll
    for (int d = 1; d < 64; d <<= 1) {
        unsigned o = __shfl_down(s, d, 64);
        if (lane + d < 64) s += o;
    }
    if (lane == 0) wsum[wv] = s;             // wave total
    __syncthreads();
    unsigned incl = s;                       // + totals of higher-bin waves
    #pragma unroll
    for (int w2 = 1; w2 < 4; w2++) if (wv + w2 < 4) incl += wsum[wv + w2];
    unsigned above = incl - c;
    if (above < rem && rem <= incl) {        // exactly one winner thread
        aux[0] = (unsigned)t;
        aux[1] = rem - above;
    }
    __syncthreads();
}

// One persistent kernel: level-pure blocks, keys in registers, 2 one-shot
// barriers + 1 exit-flag. Selection semantics bit-identical to round 0.
__global__ __launch_bounds__(256, 2) void k_fused(Ptrs p, unsigned* histA,
        unsigned* histB, unsigned* cnt, unsigned* bar,
        unsigned long long* cand, float* out) {
    __shared__ unsigned long long lbuf[CAND_TOT];   // 16 KB (rank phase only)
    __shared__ unsigned hh[256];
    __shared__ unsigned wsum[4];
    __shared__ unsigned aux[33];

    const unsigned b = blockIdx.x;
    const int t = threadIdx.x;
    const unsigned c0 = b * CPB;
    const int lev = lev_of_chunk(c0);
    const unsigned ebase = lev_base(lev);

    // ---- Phase A: keys -> registers; block byte-1 hist; one flush ----
    unsigned keys[CPB];
    hh[t] = 0u;
    __syncthreads();
    #pragma unroll
    for (unsigned j = 0; j < CPB; j++) {
        unsigned ch = c0 + j;
        unsigned k = 0u;
        if (ch < NCHUNK) {
            unsigned loc = ch * 256u + (unsigned)t - ebase;
            const float4* cp = (const float4*)(p.cls[lev]) + (size_t)loc * 4;
            float4 v0 = cp[0], v1 = cp[1], v2 = cp[2], v3 = cp[3];
            float m = fmaxf(fmaxf(max4(v0), max4(v1)), fmaxf(max4(v2), max4(v3)));
            k = f2key(m);
            atomicAdd(&hh[k >> 24], 1u);
        }
        keys[j] = k;
    }
    __syncthreads();
    {
        unsigned v = hh[t];
        if (v) atomicAdd(&histA[(b & (HP - 1u)) * HISTSZ
                                + (unsigned)lev * 256u + (unsigned)t], v);
    }
    arrive_wait(bar, true);

    // ---- Select byte-1 for OWN level only (level-pure) ----
    unsigned cA = 0;
    #pragma unroll
    for (int pp = 0; pp < HP; pp++) cA += histA[pp * HISTSZ + lev * 256 + t];
    sel256(cA, TOPKK, wsum, aux);
    unsigned binA = aux[0], remA = aux[1];
    __syncthreads();

    // ---- Phase C: byte-2 hist of keys matching byte-1 prefix ----
    hh[t] = 0u;
    __syncthreads();
    #pragma unroll
    for (unsigned j = 0; j < CPB; j++) {
        unsigned k = keys[j];
        if ((c0 + j) < NCHUNK && (k >> 24) == binA)
            atomicAdd(&hh[(k >> 16) & 0xFFu], 1u);
    }
    __syncthreads();
    {
        unsigned v = hh[t];
        if (v) atomicAdd(&histB[(b & (HP - 1u)) * HISTSZ
                                + (unsigned)lev * 256u + (unsigned)t], v);
    }
    arrive_wait(bar + 1024, true);

    // ---- Select byte-2 -> 16-bit threshold (identical semantics) ----
    unsigned cB = 0;
    #pragma unroll
    for (int pp = 0; pp < HP; pp++) cB += histB[pp * HISTSZ + lev * 256 + t];
    sel256(cB, remA, wsum, aux);
    unsigned thresh = (binA << 24) | (aux[0] << 16);
    __syncthreads();

    // ---- Phase E: compact candidates (plain cand stores; released below) ----
    #pragma unroll
    for (unsigned j = 0; j < CPB; j++) {
        unsigned ch = c0 + j;
        unsigned k = keys[j];
        if (ch < NCHUNK && k >= thresh) {
            unsigned loc = ch * 256u + (unsigned)t - ebase;
            unsigned part = ch & (NPART - 1u);
            unsigned slot = atomicAdd(&cnt[lev * NPART + part], 1u);
            if (slot < PART_CAP)
                cand[((size_t)(lev * NPART + part)) * PART_CAP + slot] =
                    ((unsigned long long)k << 32) | (unsigned)(~loc);
        }
    }

    // ---- Exit-flag: everyone arrives (release), only rank blocks wait ----
    bool ranker = b < (unsigned)(NLEV * 8);
    arrive_wait(bar + 2048, ranker);
    if (!ranker) return;

    // ---- Phase F: rank-by-counting + emit (verbatim verified round-0) ----
    const float MAXD = 4.135166556742356f;   // log(1000/16)
    int l = (int)(b >> 3);
    unsigned sl = b & 7u;

    if (t < NPART) {
        unsigned cc = cnt[l * NPART + t];
        aux[t] = (cc > PART_CAP) ? PART_CAP : cc;
    }
    __syncthreads();
    if (t == 0) {
        unsigned o = 0;
        for (int pp = 0; pp < NPART; pp++) { aux[16 + pp] = o; o += aux[pp]; }
        aux[32] = (o > CAND_TOT) ? CAND_TOT : o;
    }
    __syncthreads();
    unsigned n = aux[32];
    for (int pp = 0; pp < NPART; pp++) {
        unsigned cc = aux[pp], o = aux[16 + pp];
        for (unsigned e = (unsigned)t; e < cc; e += 256u) {
            unsigned dst = o + e;
            if (dst < CAND_TOT)
                lbuf[dst] = cand[((size_t)(l * NPART + pp)) * PART_CAP + e];
        }
    }
    __syncthreads();

    unsigned j = sl * 256u + (unsigned)t;
    if (j >= n) return;
    unsigned long long my = lbuf[j];
    unsigned rank = 0;
    #pragma unroll 8
    for (unsigned q = 0; q < n; q++) rank += (lbuf[q] > my) ? 1u : 0u;
    if (rank >= TOPKK) return;

    unsigned idx = ~((unsigned)(my & 0xFFFFFFFFull));
    float4 an = ((const float4*)p.anc[l])[idx];
    float4 dd = ((const float4*)p.reg[l])[(size_t)idx * 2];
    float w = an.z - an.x, h = an.w - an.y;
    float cx = an.x + 0.5f * w, cy = an.y + 0.5f * h;
    float pcx = cx + dd.x * w, pcy = cy + dd.y * h;
    float pw = w * expf(fminf(dd.z, MAXD));
    float ph = h * expf(fminf(dd.w, MAXD));
    float bx = pcx - 0.5f * pw, by = pcy - 0.5f * ph;
    float bz = pcx + 0.5f * pw, bw = pcy + 0.5f * ph;

    const float4* cp = (const float4*)(p.cls[l]) + (size_t)idx * 4;
    float sg[16];
    #pragma unroll
    for (int g = 0; g < 4; g++) {
        float4 v = cp[g];
        sg[4 * g + 0] = 1.0f / (1.0f + expf(-v.x));
        sg[4 * g + 1] = 1.0f / (1.0f + expf(-v.y));
        sg[4 * g + 2] = 1.0f / (1.0f + expf(-v.z));
        sg[4 * g + 3] = 1.0f / (1.0f + expf(-v.w));
    }
    // 16 rows of [bx,by,bz,bw,score,tag] == 24 float4s, 384B contiguous
    float4* q = (float4*)(out + (size_t)(l * TOPKK + rank) * (NCLS * 6));
    #pragma unroll
    for (int g = 0; g < 8; g++) {
        float ta = (float)(2 * g + 1), tb = (float)(2 * g + 2);
        q[3 * g + 0] = make_float4(bx, by, bz, bw);
        q[3 * g + 1] = make_float4(sg[2 * g], ta, bx, by);
        q[3 * g + 2] = make_float4(bz, bw, sg[2 * g + 1], tb);
    }
}

extern "C" void kernel_launch(void* const* d_in, const int* in_sizes, int n_in,
                              void* d_out, int out_size, void* d_ws, size_t ws_size,
                              hipStream_t stream) {
    (void)in_sizes; (void)n_in; (void)out_size; (void)ws_size;
    Ptrs p;
    for (int l = 0; l < NLEV; l++) {
        p.anc[l] = (const float*)d_in[3 * l + 0];
        p.cls[l] = (const float*)d_in[3 * l + 1];
        p.reg[l] = (const float*)d_in[3 * l + 2];
    }

    char* w = (char*)d_ws;
    // layout (bytes):
    //   histA : 0     .. 20480  \
    //   histB : 20480 .. 40960   } one contiguous memset (53568 B)
    //   cnt   : 40960 .. 41280   }
    //   bar   : 41280 .. 53568  /   3 one-shot sets x 4096 B (64B-aligned)
    //   cand  : 53568 .. 217408     (guarded by cnt, no memset)
    unsigned* histA = (unsigned*)w;
    unsigned* histB = (unsigned*)(w + 20480);
    unsigned* cnt   = (unsigned*)(w + 40960);
    unsigned* bar   = (unsigned*)(w + 41280);
    unsigned long long* cand = (unsigned long long*)(w + 53568);
    float* out = (float*)d_out;

    (void)hipMemsetAsync(w, 0, 53568, stream);
    // NB=512 blocks of 256 with __launch_bounds__(256,2): co-residency
    // verified on this harness in round 4 (identical config completed).
    k_fused<<<dim3(NB), dim3(256), 0, stream>>>(p, histA, histB, cnt, bar,
                                                cand, out);
}

// Round 6
// 192.691 us; speedup vs baseline: 1.1808x; 1.0484x over previous
//
#include <hip/hip_runtime.h>
#include <math.h>

#define NLEV 5
#define TOPKK 1000
#define NCLS 16
#define NPART 16                 // cand partitions (by chunk id)
#define HP 16u                   // histogram partial copies (was 4)
#define PART_CAP 256
#define CAND_TOT 2048
#define NCHUNK 3069u             // 785664 / 256
#define CPB 6u                   // chunks per block: 512*6 = 3072 >= 3069
#define NB 512u                  // co-residency VERIFIED (rounds 4 & 5 completed)
#define HISTSZ (NLEV * 256)      // 1280 u32 per copy
#define BAR_STRIDE 1024u         // u32 per barrier instance (4 KB)

// chunk-index level boundaries: 2304, 2880, 3024, 3060 — ALL divisible by
// CPB=6, so every block's 6 chunks belong to ONE level (level-pure blocks).
__device__ __forceinline__ int lev_of_chunk(unsigned c) {
    if (c < 2304u) return 0;
    if (c < 2880u) return 1;
    if (c < 3024u) return 2;
    if (c < 3060u) return 3;
    return 4;
}
__device__ __forceinline__ unsigned lev_base(int l) {   // entry base per level
    unsigned b = 0u;
    if (l == 1) b = 589824u;
    if (l == 2) b = 737280u;
    if (l == 3) b = 774144u;
    if (l == 4) b = 783360u;
    return b;
}

struct Ptrs {
    const float* anc[NLEV];
    const float* cls[NLEV];
    const float* reg[NLEV];
};

// order-preserving float32 -> uint32 (larger uint == larger float)
__device__ __forceinline__ unsigned f2key(float f) {
    unsigned u = __float_as_uint(f);
    return (u & 0x80000000u) ? ~u : (u | 0x80000000u);
}

__device__ __forceinline__ float max4(float4 v) {
    return fmaxf(fmaxf(v.x, v.y), fmaxf(v.z, v.w));
}

// ---- store-based grid barrier (v4) --------------------------------------
// Round-4->5 showed per-barrier cost ~28us is NOT arrival-counter width:
// it is same-line RMW serialization + stragglers. v4 removes ALL RMWs:
//   flags[b]  = inst[b]           b = 0..511 (one word per block, plain
//                                 relaxed atomic store -> fully parallel)
//   go[g]     = inst[768 + g*16]  16 relay lines, fanned out by block 0
// Block 0 (all 256 threads) sweeps the 2KB flag array (~1 LLC round-trip
// per sweep) and fans out. One-shot instances; memset zeroes per launch
// (rocprof-replay-safe: every timed launch re-runs the memset first).
__device__ __forceinline__ void bar_arrive(unsigned* inst) {
    if (threadIdx.x == 0) {
        __builtin_amdgcn_fence(__ATOMIC_RELEASE, "agent");
        __hip_atomic_store(inst + blockIdx.x, 1u, __ATOMIC_RELAXED,
                           __HIP_MEMORY_SCOPE_AGENT);
    }
}

// block 0 only, ALL threads participate
__device__ __forceinline__ void bar_monitor_fanout(unsigned* inst, unsigned* wsh) {
    for (;;) {
        unsigned f0 = __hip_atomic_load(inst + (unsigned)threadIdx.x,
                        __ATOMIC_RELAXED, __HIP_MEMORY_SCOPE_AGENT);
        unsigned f1 = __hip_atomic_load(inst + 256u + (unsigned)threadIdx.x,
                        __ATOMIC_RELAXED, __HIP_MEMORY_SCOPE_AGENT);
        unsigned long long bal = __ballot(f0 != 0u && f1 != 0u);
        if ((threadIdx.x & 63) == 0)
            wsh[threadIdx.x >> 6] = (bal == 0xFFFFFFFFFFFFFFFFull) ? 1u : 0u;
        __syncthreads();
        bool done = wsh[0] && wsh[1] && wsh[2] && wsh[3];
        __syncthreads();
        if (done) break;
        __builtin_amdgcn_s_sleep(2);
    }
    if (threadIdx.x < 16)
        __hip_atomic_store(inst + 768u + (unsigned)threadIdx.x * 16u, 1u,
                           __ATOMIC_RELAXED, __HIP_MEMORY_SCOPE_AGENT);
}

__device__ __forceinline__ void bar_waitgo(unsigned* inst) {
    unsigned g = blockIdx.x & 15u;
    while (!__hip_atomic_load(inst + 768u + g * 16u, __ATOMIC_RELAXED,
                              __HIP_MEMORY_SCOPE_AGENT))
        __builtin_amdgcn_s_sleep(4);
    __builtin_amdgcn_fence(__ATOMIC_ACQUIRE, "agent");
}

__device__ __forceinline__ void gridbar(unsigned* inst, unsigned* wsh) {
    __syncthreads();
    bar_arrive(inst);
    if (blockIdx.x == 0) {
        bar_monitor_fanout(inst, wsh);
        if (threadIdx.x == 0)
            __builtin_amdgcn_fence(__ATOMIC_ACQUIRE, "agent");
    } else if (threadIdx.x == 0) {
        bar_waitgo(inst);
    }
    __syncthreads();
}

// suffix-select over 256 bins (bin == threadIdx) via wave shuffles.
// Finds bin holding the rem-th largest; aux[0]=bin, aux[1]=remainder.
// (verbatim round-5 core, absmax-0 verified)
__device__ __forceinline__ void sel256(unsigned c, unsigned rem,
                                       unsigned* wsum, unsigned* aux) {
    int t = threadIdx.x, lane = t & 63, wv = t >> 6;
    unsigned s = c;                          // suffix-sum over lanes >= mine
    #pragma unroll
    for (int d = 1; d < 64; d <<= 1) {
        unsigned o = __shfl_down(s, d, 64);
        if (lane + d < 64) s += o;
    }
    if (lane == 0) wsum[wv] = s;             // wave total
    __syncthreads();
    unsigned incl = s;                       // + totals of higher-bin waves
    #pragma unroll
    for (int w2 = 1; w2 < 4; w2++) if (wv + w2 < 4) incl += wsum[wv + w2];
    unsigned above = incl - c;
    if (above < rem && rem <= incl) {        // exactly one winner thread
        aux[0] = (unsigned)t;
        aux[1] = rem - above;
    }
    __syncthreads();
}

// One persistent kernel: level-pure blocks, keys in registers, store-based
// barriers, contention-free counters. Selection bit-identical to round 0.
__global__ __launch_bounds__(256, 2) void k_fused(Ptrs p, unsigned* histA,
        unsigned* histB, unsigned* cnt, unsigned* bar,
        unsigned long long* cand, float* out) {
    __shared__ unsigned long long lbuf[CAND_TOT];   // 16 KB (rank phase only)
    __shared__ unsigned hh[256];
    __shared__ unsigned wsum[4];
    __shared__ unsigned wsh[4];
    __shared__ unsigned aux[33];

    const unsigned b = blockIdx.x;
    const int t = threadIdx.x;
    const unsigned c0 = b * CPB;
    const int lev = lev_of_chunk(c0);
    const unsigned ebase = lev_base(lev);
    unsigned* bar0 = bar;
    unsigned* bar1 = bar + BAR_STRIDE;
    unsigned* bar2 = bar + 2u * BAR_STRIDE;

    // ---- Phase A1: all 24 loads + fmax first (no LDS ops in the way) ----
    unsigned keys[CPB];
    #pragma unroll
    for (unsigned j = 0; j < CPB; j++) {
        unsigned ch = c0 + j;
        unsigned k = 0u;
        if (ch < NCHUNK) {
            unsigned loc = ch * 256u + (unsigned)t - ebase;
            const float4* cp = (const float4*)(p.cls[lev]) + (size_t)loc * 4;
            float4 v0 = cp[0], v1 = cp[1], v2 = cp[2], v3 = cp[3];
            float m = fmaxf(fmaxf(max4(v0), max4(v1)), fmaxf(max4(v2), max4(v3)));
            k = f2key(m);
        }
        keys[j] = k;
    }
    // ---- Phase A2: block byte-1 hist; one flush into 1-of-16 copies ----
    hh[t] = 0u;
    __syncthreads();
    #pragma unroll
    for (unsigned j = 0; j < CPB; j++)
        if (c0 + j < NCHUNK) atomicAdd(&hh[keys[j] >> 24], 1u);
    __syncthreads();
    {
        unsigned v = hh[t];
        if (v) atomicAdd(&histA[(b & (HP - 1u)) * HISTSZ
                                + (unsigned)lev * 256u + (unsigned)t], v);
    }
    gridbar(bar0, wsh);

    // ---- Select byte-1 for OWN level only (level-pure) ----
    unsigned cA = 0;
    #pragma unroll
    for (unsigned pp = 0; pp < HP; pp++) cA += histA[pp * HISTSZ + lev * 256 + t];
    sel256(cA, TOPKK, wsum, aux);
    unsigned binA = aux[0], remA = aux[1];
    __syncthreads();

    // ---- Phase C: byte-2 hist of keys matching byte-1 prefix ----
    hh[t] = 0u;
    __syncthreads();
    #pragma unroll
    for (unsigned j = 0; j < CPB; j++) {
        unsigned k = keys[j];
        if ((c0 + j) < NCHUNK && (k >> 24) == binA)
            atomicAdd(&hh[(k >> 16) & 0xFFu], 1u);
    }
    __syncthreads();
    {
        unsigned v = hh[t];
        if (v) atomicAdd(&histB[(b & (HP - 1u)) * HISTSZ
                                + (unsigned)lev * 256u + (unsigned)t], v);
    }
    gridbar(bar1, wsh);

    // ---- Select byte-2 -> 16-bit threshold (identical semantics) ----
    unsigned cB = 0;
    #pragma unroll
    for (unsigned pp = 0; pp < HP; pp++) cB += histB[pp * HISTSZ + lev * 256 + t];
    sel256(cB, remA, wsum, aux);
    unsigned thresh = (binA << 24) | (aux[0] << 16);
    __syncthreads();

    // ---- Phase E: compact candidates (cnt padded: 1 counter / cacheline;
    //      cand order irrelevant — rank is order-independent) ----
    #pragma unroll
    for (unsigned j = 0; j < CPB; j++) {
        unsigned ch = c0 + j;
        unsigned k = keys[j];
        if (ch < NCHUNK && k >= thresh) {
            unsigned loc = ch * 256u + (unsigned)t - ebase;
            unsigned part = ch & (NPART - 1u);
            unsigned slot = atomicAdd(&cnt[(lev * NPART + part) * 16u], 1u);
            if (slot < PART_CAP)
                cand[((size_t)(lev * NPART + part)) * PART_CAP + slot] =
                    ((unsigned long long)k << 32) | (unsigned)(~loc);
        }
    }

    // ---- Exit-flag: everyone arrives; only rank blocks (0..39) wait ----
    bool ranker = b < (unsigned)(NLEV * 8);
    __syncthreads();
    bar_arrive(bar2);
    if (b == 0) {
        bar_monitor_fanout(bar2, wsh);
        if (t == 0) __builtin_amdgcn_fence(__ATOMIC_ACQUIRE, "agent");
    } else if (ranker) {
        if (t == 0) bar_waitgo(bar2);
    } else {
        return;
    }
    __syncthreads();

    // ---- Phase F: rank-by-counting + emit (verbatim verified round-0) ----
    const float MAXD = 4.135166556742356f;   // log(1000/16)
    int l = (int)(b >> 3);
    unsigned sl = b & 7u;

    if (t < NPART) {
        unsigned cc = cnt[(l * NPART + t) * 16u];
        aux[t] = (cc > PART_CAP) ? PART_CAP : cc;
    }
    __syncthreads();
    if (t == 0) {
        unsigned o = 0;
        for (int pp = 0; pp < NPART; pp++) { aux[16 + pp] = o; o += aux[pp]; }
        aux[32] = (o > CAND_TOT) ? CAND_TOT : o;
    }
    __syncthreads();
    unsigned n = aux[32];
    for (int pp = 0; pp < NPART; pp++) {
        unsigned cc = aux[pp], o = aux[16 + pp];
        for (unsigned e = (unsigned)t; e < cc; e += 256u) {
            unsigned dst = o + e;
            if (dst < CAND_TOT)
                lbuf[dst] = cand[((size_t)(l * NPART + pp)) * PART_CAP + e];
        }
    }
    __syncthreads();

    unsigned j = sl * 256u + (unsigned)t;
    if (j >= n) return;
    unsigned long long my = lbuf[j];
    unsigned rank = 0;
    #pragma unroll 8
    for (unsigned q = 0; q < n; q++) rank += (lbuf[q] > my) ? 1u : 0u;
    if (rank >= TOPKK) return;

    unsigned idx = ~((unsigned)(my & 0xFFFFFFFFull));
    float4 an = ((const float4*)p.anc[l])[idx];
    float4 dd = ((const float4*)p.reg[l])[(size_t)idx * 2];
    float w = an.z - an.x, h = an.w - an.y;
    float cx = an.x + 0.5f * w, cy = an.y + 0.5f * h;
    float pcx = cx + dd.x * w, pcy = cy + dd.y * h;
    float pw = w * expf(fminf(dd.z, MAXD));
    float ph = h * expf(fminf(dd.w, MAXD));
    float bx = pcx - 0.5f * pw, by = pcy - 0.5f * ph;
    float bz = pcx + 0.5f * pw, bw = pcy + 0.5f * ph;

    const float4* cp = (const float4*)(p.cls[l]) + (size_t)idx * 4;
    float sg[16];
    #pragma unroll
    for (int g = 0; g < 4; g++) {
        float4 v = cp[g];
        sg[4 * g + 0] = 1.0f / (1.0f + expf(-v.x));
        sg[4 * g + 1] = 1.0f / (1.0f + expf(-v.y));
        sg[4 * g + 2] = 1.0f / (1.0f + expf(-v.z));
        sg[4 * g + 3] = 1.0f / (1.0f + expf(-v.w));
    }
    // 16 rows of [bx,by,bz,bw,score,tag] == 24 float4s, 384B contiguous
    float4* q = (float4*)(out + (size_t)(l * TOPKK + rank) * (NCLS * 6));
    #pragma unroll
    for (int g = 0; g < 8; g++) {
        float ta = (float)(2 * g + 1), tb = (float)(2 * g + 2);
        q[3 * g + 0] = make_float4(bx, by, bz, bw);
        q[3 * g + 1] = make_float4(sg[2 * g], ta, bx, by);
        q[3 * g + 2] = make_float4(bz, bw, sg[2 * g + 1], tb);
    }
}

extern "C" void kernel_launch(void* const* d_in, const int* in_sizes, int n_in,
                              void* d_out, int out_size, void* d_ws, size_t ws_size,
                              hipStream_t stream) {
    (void)in_sizes; (void)n_in; (void)out_size; (void)ws_size;
    Ptrs p;
    for (int l = 0; l < NLEV; l++) {
        p.anc[l] = (const float*)d_in[3 * l + 0];
        p.cls[l] = (const float*)d_in[3 * l + 1];
        p.reg[l] = (const float*)d_in[3 * l + 2];
    }

    char* w = (char*)d_ws;
    // layout (bytes):
    //   histA : 0      .. 81920   \   16 copies x 5120 B
    //   histB : 81920  .. 163840   }  one contiguous memset (181248 B)
    //   cnt   : 163840 .. 168960   }  80 counters x 64 B (1 line each)
    //   bar   : 168960 .. 181248  /   3 one-shot store-based sets x 4096 B
    //   cand  : 181248 .. 345088      (guarded by cnt, no memset)
    unsigned* histA = (unsigned*)w;
    unsigned* histB = (unsigned*)(w + 81920);
    unsigned* cnt   = (unsigned*)(w + 163840);
    unsigned* bar   = (unsigned*)(w + 168960);
    unsigned long long* cand = (unsigned long long*)(w + 181248);
    float* out = (float*)d_out;

    (void)hipMemsetAsync(w, 0, 181248, stream);
    // NB=512 blocks of 256 with __launch_bounds__(256,2): co-residency
    // verified on this harness in rounds 4 and 5 (identical config).
    k_fused<<<dim3(NB), dim3(256), 0, stream>>>(p, histA, histB, cnt, bar,
                                                cand, out);
}

// Round 7
// 167.754 us; speedup vs baseline: 1.3563x; 1.1487x over previous
//
#include <hip/hip_runtime.h>
#include <math.h>

#define NLEV 5
#define TOPKK 1000
#define NCLS 16
#define NPART 16                 // cand partitions (by chunk id)
#define HP 16u                   // histogram partial copies
#define PART_CAP 256
#define CAND_TOT 2048
#define NCHUNK 3069u             // 785664 / 256
#define CPB 6u                   // chunks per block: 512*6 = 3072 >= 3069
#define NB 512u                  // co-residency VERIFIED (rounds 4-6 completed)
#define HISTSZ (NLEV * 256)      // 1280 u32 per copy
#define BAR_STRIDE 1024u         // u32 per barrier instance (4 KB)

// LLC-coherent accessors: agent-scope relaxed atomics bypass the (possibly
// stale / dirty) per-XCD L2 and serialize at the LLC. Using these for ALL
// cross-block data lets the grid barrier drop its release/acquire fences,
// whose gfx950 lowering (buffer_wbl2 / buffer_inv = full-L2 writeback /
// invalidate, x512 leaders x3 barriers) dominated rounds 2-6.
__device__ __forceinline__ unsigned g_load(const unsigned* p) {
    return __hip_atomic_load(p, __ATOMIC_RELAXED, __HIP_MEMORY_SCOPE_AGENT);
}
__device__ __forceinline__ unsigned long long g_load64(const unsigned long long* p) {
    return __hip_atomic_load(p, __ATOMIC_RELAXED, __HIP_MEMORY_SCOPE_AGENT);
}
__device__ __forceinline__ void g_store(unsigned* p, unsigned v) {
    __hip_atomic_store(p, v, __ATOMIC_RELAXED, __HIP_MEMORY_SCOPE_AGENT);
}
__device__ __forceinline__ void g_store64(unsigned long long* p, unsigned long long v) {
    __hip_atomic_store(p, v, __ATOMIC_RELAXED, __HIP_MEMORY_SCOPE_AGENT);
}

// chunk-index level boundaries: 2304, 2880, 3024, 3060 — ALL divisible by
// CPB=6, so every block's 6 chunks belong to ONE level (level-pure blocks).
__device__ __forceinline__ int lev_of_chunk(unsigned c) {
    if (c < 2304u) return 0;
    if (c < 2880u) return 1;
    if (c < 3024u) return 2;
    if (c < 3060u) return 3;
    return 4;
}
__device__ __forceinline__ unsigned lev_base(int l) {   // entry base per level
    unsigned b = 0u;
    if (l == 1) b = 589824u;
    if (l == 2) b = 737280u;
    if (l == 3) b = 774144u;
    if (l == 4) b = 783360u;
    return b;
}

struct Ptrs {
    const float* anc[NLEV];
    const float* cls[NLEV];
    const float* reg[NLEV];
};

// order-preserving float32 -> uint32 (larger uint == larger float)
__device__ __forceinline__ unsigned f2key(float f) {
    unsigned u = __float_as_uint(f);
    return (u & 0x80000000u) ? ~u : (u | 0x80000000u);
}

__device__ __forceinline__ float max4(float4 v) {
    return fmaxf(fmaxf(v.x, v.y), fmaxf(v.z, v.w));
}

// ---- fence-free store-based grid barrier --------------------------------
//   flags[b] = inst[b]           b = 0..511 (one word/block, relaxed store)
//   go[g]    = inst[768 + g*16]  16 relay lines, fanned out by block 0
// ORDERING: __syncthreads() before arrival drains vmcnt(0) in EVERY wave
// (HIP emits s_waitcnt vmcnt(0) lgkmcnt(0) before s_barrier), so all of the
// block's LLC-bound atomics have completed before the flag store. All
// cross-block data moves via agent-scope atomics (LLC = serialization
// point), so flag-observed => data-visible. NO wbl2/inv anywhere.
__device__ __forceinline__ void bar_arrive(unsigned* inst) {
    if (threadIdx.x == 0) g_store(inst + blockIdx.x, 1u);
}

// block 0 only, ALL threads participate
__device__ __forceinline__ void bar_monitor_fanout(unsigned* inst, unsigned* wsh) {
    for (;;) {
        unsigned f0 = g_load(inst + (unsigned)threadIdx.x);
        unsigned f1 = g_load(inst + 256u + (unsigned)threadIdx.x);
        unsigned long long bal = __ballot(f0 != 0u && f1 != 0u);
        if ((threadIdx.x & 63) == 0)
            wsh[threadIdx.x >> 6] = (bal == 0xFFFFFFFFFFFFFFFFull) ? 1u : 0u;
        __syncthreads();
        bool done = wsh[0] && wsh[1] && wsh[2] && wsh[3];
        __syncthreads();
        if (done) break;
        __builtin_amdgcn_s_sleep(2);
    }
    if (threadIdx.x < 16)
        g_store(inst + 768u + (unsigned)threadIdx.x * 16u, 1u);
}

__device__ __forceinline__ void bar_waitgo(unsigned* inst) {
    unsigned g = blockIdx.x & 15u;
    while (!g_load(inst + 768u + g * 16u))
        __builtin_amdgcn_s_sleep(4);
}

__device__ __forceinline__ void gridbar(unsigned* inst, unsigned* wsh) {
    __syncthreads();                       // drains vmcnt in all waves
    bar_arrive(inst);
    if (blockIdx.x == 0) {
        bar_monitor_fanout(inst, wsh);
    } else if (threadIdx.x == 0) {
        bar_waitgo(inst);
    }
    __syncthreads();
}

// suffix-select over 256 bins (bin == threadIdx) via wave shuffles.
// Finds bin holding the rem-th largest; aux[0]=bin, aux[1]=remainder.
// (verbatim round-5/6 core, absmax-0 verified)
__device__ __forceinline__ void sel256(unsigned c, unsigned rem,
                                       unsigned* wsum, unsigned* aux) {
    int t = threadIdx.x, lane = t & 63, wv = t >> 6;
    unsigned s = c;                          // suffix-sum over lanes >= mine
    #pragma unroll
    for (int d = 1; d < 64; d <<= 1) {
        unsigned o = __shfl_down(s, d, 64);
        if (lane + d < 64) s += o;
    }
    if (lane == 0) wsum[wv] = s;             // wave total
    __syncthreads();
    unsigned incl = s;                       // + totals of higher-bin waves
    #pragma unroll
    for (int w2 = 1; w2 < 4; w2++) if (wv + w2 < 4) incl += wsum[wv + w2];
    unsigned above = incl - c;
    if (above < rem && rem <= incl) {        // exactly one winner thread
        aux[0] = (unsigned)t;
        aux[1] = rem - above;
    }
    __syncthreads();
}

// One persistent kernel: level-pure blocks, keys in registers, fence-free
// store-based barriers, all cross-block data via LLC atomics.
// Selection semantics bit-identical to the verified round-0 kernel.
__global__ __launch_bounds__(256, 2) void k_fused(Ptrs p, unsigned* histA,
        unsigned* histB, unsigned* cnt, unsigned* bar,
        unsigned long long* cand, float* out) {
    __shared__ unsigned long long lbuf[CAND_TOT];   // 16 KB (rank phase only)
    __shared__ unsigned hh[256];
    __shared__ unsigned wsum[4];
    __shared__ unsigned wsh[4];
    __shared__ unsigned aux[33];

    const unsigned b = blockIdx.x;
    const int t = threadIdx.x;
    const unsigned c0 = b * CPB;
    const int lev = lev_of_chunk(c0);
    const unsigned ebase = lev_base(lev);
    unsigned* bar0 = bar;
    unsigned* bar1 = bar + BAR_STRIDE;
    unsigned* bar2 = bar + 2u * BAR_STRIDE;

    // ---- Phase A1: all 24 loads + fmax first (no LDS ops in the way) ----
    unsigned keys[CPB];
    #pragma unroll
    for (unsigned j = 0; j < CPB; j++) {
        unsigned ch = c0 + j;
        unsigned k = 0u;
        if (ch < NCHUNK) {
            unsigned loc = ch * 256u + (unsigned)t - ebase;
            const float4* cp = (const float4*)(p.cls[lev]) + (size_t)loc * 4;
            float4 v0 = cp[0], v1 = cp[1], v2 = cp[2], v3 = cp[3];
            float m = fmaxf(fmaxf(max4(v0), max4(v1)), fmaxf(max4(v2), max4(v3)));
            k = f2key(m);
        }
        keys[j] = k;
    }
    // ---- Phase A2: block byte-1 hist; one flush into 1-of-16 copies ----
    hh[t] = 0u;
    __syncthreads();
    #pragma unroll
    for (unsigned j = 0; j < CPB; j++)
        if (c0 + j < NCHUNK) atomicAdd(&hh[keys[j] >> 24], 1u);
    __syncthreads();
    {
        unsigned v = hh[t];
        if (v) atomicAdd(&histA[(b & (HP - 1u)) * HISTSZ
                                + (unsigned)lev * 256u + (unsigned)t], v);
    }
    gridbar(bar0, wsh);

    // ---- Select byte-1 for OWN level only (LLC loads; level-pure) ----
    unsigned cA = 0;
    #pragma unroll
    for (unsigned pp = 0; pp < HP; pp++)
        cA += g_load(histA + pp * HISTSZ + (unsigned)lev * 256u + (unsigned)t);
    sel256(cA, TOPKK, wsum, aux);
    unsigned binA = aux[0], remA = aux[1];
    __syncthreads();

    // ---- Phase C: byte-2 hist of keys matching byte-1 prefix ----
    hh[t] = 0u;
    __syncthreads();
    #pragma unroll
    for (unsigned j = 0; j < CPB; j++) {
        unsigned k = keys[j];
        if ((c0 + j) < NCHUNK && (k >> 24) == binA)
            atomicAdd(&hh[(k >> 16) & 0xFFu], 1u);
    }
    __syncthreads();
    {
        unsigned v = hh[t];
        if (v) atomicAdd(&histB[(b & (HP - 1u)) * HISTSZ
                                + (unsigned)lev * 256u + (unsigned)t], v);
    }
    gridbar(bar1, wsh);

    // ---- Select byte-2 -> 16-bit threshold (identical semantics) ----
    unsigned cB = 0;
    #pragma unroll
    for (unsigned pp = 0; pp < HP; pp++)
        cB += g_load(histB + pp * HISTSZ + (unsigned)lev * 256u + (unsigned)t);
    sel256(cB, remA, wsum, aux);
    unsigned thresh = (binA << 24) | (aux[0] << 16);
    __syncthreads();

    // ---- Phase E: compact candidates (all stores LLC-scope) ----
    #pragma unroll
    for (unsigned j = 0; j < CPB; j++) {
        unsigned ch = c0 + j;
        unsigned k = keys[j];
        if (ch < NCHUNK && k >= thresh) {
            unsigned loc = ch * 256u + (unsigned)t - ebase;
            unsigned part = ch & (NPART - 1u);
            unsigned slot = atomicAdd(&cnt[(lev * NPART + part) * 16u], 1u);
            if (slot < PART_CAP)
                g_store64(&cand[((size_t)(lev * NPART + part)) * PART_CAP + slot],
                          ((unsigned long long)k << 32) | (unsigned)(~loc));
        }
    }

    // ---- Exit-flag: everyone arrives; only rank blocks (0..39) wait ----
    bool ranker = b < (unsigned)(NLEV * 8);
    __syncthreads();                       // drains vmcnt (cand stores done)
    bar_arrive(bar2);
    if (b == 0) {
        bar_monitor_fanout(bar2, wsh);
    } else if (ranker) {
        if (t == 0) bar_waitgo(bar2);
    } else {
        return;
    }
    __syncthreads();

    // ---- Phase F: rank-by-counting + emit (verified round-0 logic;
    //      cand/cnt reads via LLC loads) ----
    const float MAXD = 4.135166556742356f;   // log(1000/16)
    int l = (int)(b >> 3);
    unsigned sl = b & 7u;

    if (t < NPART) {
        unsigned cc = g_load(cnt + (l * NPART + t) * 16u);
        aux[t] = (cc > PART_CAP) ? PART_CAP : cc;
    }
    __syncthreads();
    if (t == 0) {
        unsigned o = 0;
        for (int pp = 0; pp < NPART; pp++) { aux[16 + pp] = o; o += aux[pp]; }
        aux[32] = (o > CAND_TOT) ? CAND_TOT : o;
    }
    __syncthreads();
    unsigned n = aux[32];
    for (int pp = 0; pp < NPART; pp++) {
        unsigned cc = aux[pp], o = aux[16 + pp];
        for (unsigned e = (unsigned)t; e < cc; e += 256u) {
            unsigned dst = o + e;
            if (dst < CAND_TOT)
                lbuf[dst] = g_load64(&cand[((size_t)(l * NPART + pp)) * PART_CAP + e]);
        }
    }
    __syncthreads();

    unsigned j = sl * 256u + (unsigned)t;
    if (j >= n) return;
    unsigned long long my = lbuf[j];
    unsigned rank = 0;
    #pragma unroll 8
    for (unsigned q = 0; q < n; q++) rank += (lbuf[q] > my) ? 1u : 0u;
    if (rank >= TOPKK) return;

    unsigned idx = ~((unsigned)(my & 0xFFFFFFFFull));
    float4 an = ((const float4*)p.anc[l])[idx];
    float4 dd = ((const float4*)p.reg[l])[(size_t)idx * 2];
    float w = an.z - an.x, h = an.w - an.y;
    float cx = an.x + 0.5f * w, cy = an.y + 0.5f * h;
    float pcx = cx + dd.x * w, pcy = cy + dd.y * h;
    float pw = w * expf(fminf(dd.z, MAXD));
    float ph = h * expf(fminf(dd.w, MAXD));
    float bx = pcx - 0.5f * pw, by = pcy - 0.5f * ph;
    float bz = pcx + 0.5f * pw, bw = pcy + 0.5f * ph;

    const float4* cp = (const float4*)(p.cls[l]) + (size_t)idx * 4;
    float sg[16];
    #pragma unroll
    for (int g = 0; g < 4; g++) {
        float4 v = cp[g];
        sg[4 * g + 0] = 1.0f / (1.0f + expf(-v.x));
        sg[4 * g + 1] = 1.0f / (1.0f + expf(-v.y));
        sg[4 * g + 2] = 1.0f / (1.0f + expf(-v.z));
        sg[4 * g + 3] = 1.0f / (1.0f + expf(-v.w));
    }
    // 16 rows of [bx,by,bz,bw,score,tag] == 24 float4s, 384B contiguous
    float4* q = (float4*)(out + (size_t)(l * TOPKK + rank) * (NCLS * 6));
    #pragma unroll
    for (int g = 0; g < 8; g++) {
        float ta = (float)(2 * g + 1), tb = (float)(2 * g + 2);
        q[3 * g + 0] = make_float4(bx, by, bz, bw);
        q[3 * g + 1] = make_float4(sg[2 * g], ta, bx, by);
        q[3 * g + 2] = make_float4(bz, bw, sg[2 * g + 1], tb);
    }
}

extern "C" void kernel_launch(void* const* d_in, const int* in_sizes, int n_in,
                              void* d_out, int out_size, void* d_ws, size_t ws_size,
                              hipStream_t stream) {
    (void)in_sizes; (void)n_in; (void)out_size; (void)ws_size;
    Ptrs p;
    for (int l = 0; l < NLEV; l++) {
        p.anc[l] = (const float*)d_in[3 * l + 0];
        p.cls[l] = (const float*)d_in[3 * l + 1];
        p.reg[l] = (const float*)d_in[3 * l + 2];
    }

    char* w = (char*)d_ws;
    // layout (bytes):
    //   histA : 0      .. 81920   \   16 copies x 5120 B
    //   histB : 81920  .. 163840   }  one contiguous memset (181248 B)
    //   cnt   : 163840 .. 168960   }  80 counters x 64 B (1 line each)
    //   bar   : 168960 .. 181248  /   3 one-shot store-based sets x 4096 B
    //   cand  : 181248 .. 345088      (guarded by cnt, no memset)
    unsigned* histA = (unsigned*)w;
    unsigned* histB = (unsigned*)(w + 81920);
    unsigned* cnt   = (unsigned*)(w + 163840);
    unsigned* bar   = (unsigned*)(w + 168960);
    unsigned long long* cand = (unsigned long long*)(w + 181248);
    float* out = (float*)d_out;

    (void)hipMemsetAsync(w, 0, 181248, stream);
    // NB=512 blocks of 256 with __launch_bounds__(256,2): co-residency
    // verified on this harness in rounds 4-6 (identical config).
    k_fused<<<dim3(NB), dim3(256), 0, stream>>>(p, histA, histB, cnt, bar,
                                                cand, out);
}

// Round 8
// 166.858 us; speedup vs baseline: 1.3636x; 1.0054x over previous
//
#include <hip/hip_runtime.h>
#include <math.h>

#define NLEV 5
#define TOPKK 1000
#define NCLS 16
#define NPART 16                 // cand partitions (by chunk id)
#define HP 16u                   // histogram partial copies
#define PART_CAP 256
#define CAND_TOT 2048
#define NCHUNK 3069u             // 785664 / 256
#define HISTSZ (NLEV * 256)      // 1280 u32 per copy
#define BAR_STRIDE 2048u         // u32 per barrier instance (8 KB): flags[0..NB-1], relays @1024

// LLC-coherent accessors: agent-scope relaxed atomics bypass per-XCD L2 and
// serialize at the LLC. All cross-block data uses these, so the grid barrier
// needs NO release/acquire fences (gfx950 fences lower to buffer_wbl2 /
// buffer_inv = full-L2 writeback/invalidate -- measured ~7us/barrier, r6->r7).
__device__ __forceinline__ unsigned g_load(const unsigned* p) {
    return __hip_atomic_load(p, __ATOMIC_RELAXED, __HIP_MEMORY_SCOPE_AGENT);
}
__device__ __forceinline__ unsigned long long g_load64(const unsigned long long* p) {
    return __hip_atomic_load(p, __ATOMIC_RELAXED, __HIP_MEMORY_SCOPE_AGENT);
}
__device__ __forceinline__ void g_store(unsigned* p, unsigned v) {
    __hip_atomic_store(p, v, __ATOMIC_RELAXED, __HIP_MEMORY_SCOPE_AGENT);
}
__device__ __forceinline__ void g_store64(unsigned long long* p, unsigned long long v) {
    __hip_atomic_store(p, v, __ATOMIC_RELAXED, __HIP_MEMORY_SCOPE_AGENT);
}

// chunk-index level boundaries: 2304, 2880, 3024, 3060 — divisible by BOTH
// 3 and 6, so blocks are level-pure for CPB=3 (NB=1023, exact: 3*1023=3069)
// and CPB=6 (NB=512, tail-guarded).
__device__ __forceinline__ int lev_of_chunk(unsigned c) {
    if (c < 2304u) return 0;
    if (c < 2880u) return 1;
    if (c < 3024u) return 2;
    if (c < 3060u) return 3;
    return 4;
}
__device__ __forceinline__ unsigned lev_base(int l) {   // entry base per level
    unsigned b = 0u;
    if (l == 1) b = 589824u;
    if (l == 2) b = 737280u;
    if (l == 3) b = 774144u;
    if (l == 4) b = 783360u;
    return b;
}

struct Ptrs {
    const float* anc[NLEV];
    const float* cls[NLEV];
    const float* reg[NLEV];
};

// order-preserving float32 -> uint32 (larger uint == larger float)
__device__ __forceinline__ unsigned f2key(float f) {
    unsigned u = __float_as_uint(f);
    return (u & 0x80000000u) ? ~u : (u | 0x80000000u);
}

__device__ __forceinline__ float max4(float4 v) {
    return fmaxf(fmaxf(v.x, v.y), fmaxf(v.z, v.w));
}

// ---- fence-free store-based grid barrier (r7-verified design) -----------
//   flags[b] = inst[b]            one word per block, relaxed store
//   go[g]    = inst[1024 + g*16]  16 relay lines, fanned out by block 0
// ORDERING: __syncthreads() before arrival drains vmcnt(0) in every wave, so
// all the block's LLC-bound atomics complete before the flag store; all
// cross-block data moves via agent-scope atomics (LLC = serialization
// point) => flag-observed implies data-visible. No wbl2/inv anywhere.
__device__ __forceinline__ void bar_arrive(unsigned* inst) {
    if (threadIdx.x == 0) g_store(inst + blockIdx.x, 1u);
}

// block 0 only, ALL threads participate
template<unsigned NBV>
__device__ __forceinline__ void bar_monitor_fanout(unsigned* inst, unsigned* wsh) {
    constexpr unsigned W = (NBV + 255u) / 256u;
    for (;;) {
        bool all = true;
        #pragma unroll
        for (unsigned i = 0; i < W; i++) {
            unsigned idx = i * 256u + (unsigned)threadIdx.x;
            unsigned f = (idx < NBV) ? g_load(inst + idx) : 1u;
            all = all && (f != 0u);
        }
        unsigned long long bal = __ballot(all);
        if ((threadIdx.x & 63) == 0)
            wsh[threadIdx.x >> 6] = (bal == 0xFFFFFFFFFFFFFFFFull) ? 1u : 0u;
        __syncthreads();
        bool done = wsh[0] && wsh[1] && wsh[2] && wsh[3];
        __syncthreads();
        if (done) break;
        __builtin_amdgcn_s_sleep(2);
    }
    if (threadIdx.x < 16)
        g_store(inst + 1024u + (unsigned)threadIdx.x * 16u, 1u);
}

__device__ __forceinline__ void bar_waitgo(unsigned* inst) {
    unsigned g = blockIdx.x & 15u;
    while (!g_load(inst + 1024u + g * 16u))
        __builtin_amdgcn_s_sleep(4);
}

template<unsigned NBV>
__device__ __forceinline__ void gridbar(unsigned* inst, unsigned* wsh) {
    __syncthreads();                       // drains vmcnt in all waves
    bar_arrive(inst);
    if (blockIdx.x == 0) {
        bar_monitor_fanout<NBV>(inst, wsh);
    } else if (threadIdx.x == 0) {
        bar_waitgo(inst);
    }
    __syncthreads();
}

// suffix-select over 256 bins (bin == threadIdx) via wave shuffles.
// Finds bin holding the rem-th largest; aux[0]=bin, aux[1]=remainder.
// (verbatim r5-r7 core, absmax-0 verified)
__device__ __forceinline__ void sel256(unsigned c, unsigned rem,
                                       unsigned* wsum, unsigned* aux) {
    int t = threadIdx.x, lane = t & 63, wv = t >> 6;
    unsigned s = c;                          // suffix-sum over lanes >= mine
    #pragma unroll
    for (int d = 1; d < 64; d <<= 1) {
        unsigned o = __shfl_down(s, d, 64);
        if (lane + d < 64) s += o;
    }
    if (lane == 0) wsum[wv] = s;             // wave total
    __syncthreads();
    unsigned incl = s;                       // + totals of higher-bin waves
    #pragma unroll
    for (int w2 = 1; w2 < 4; w2++) if (wv + w2 < 4) incl += wsum[wv + w2];
    unsigned above = incl - c;
    if (above < rem && rem <= incl) {        // exactly one winner thread
        aux[0] = (unsigned)t;
        aux[1] = rem - above;
    }
    __syncthreads();
}

// One persistent kernel: level-pure blocks, keys in registers, fence-free
// barriers, LLC-scope cross-block data. Templated on CPB/NB so the host can
// pick 1023-block (4/CU, 2x TLP for the HBM/LLC-bound phase A) when the
// occupancy API guarantees residency, else the r7-verified 512-block shape.
template<unsigned CPBV, unsigned NBV>
__global__ __launch_bounds__(256, 2) void k_fused(Ptrs p, unsigned* histA,
        unsigned* histB, unsigned* cnt, unsigned* bar,
        unsigned long long* cand, float* out) {
    __shared__ unsigned long long lbuf[CAND_TOT];   // 16 KB (rank phase only)
    __shared__ unsigned hh[256];
    __shared__ unsigned wsum[4];
    __shared__ unsigned wsh[4];
    __shared__ unsigned aux[33];

    const unsigned b = blockIdx.x;
    const int t = threadIdx.x;
    const unsigned c0 = b * CPBV;
    const int lev = lev_of_chunk(c0);
    const unsigned ebase = lev_base(lev);
    unsigned* bar0 = bar;
    unsigned* bar1 = bar + BAR_STRIDE;
    unsigned* bar2 = bar + 2u * BAR_STRIDE;

    // ---- Phase A1: all loads + fmax first (no LDS ops in the way) ----
    unsigned keys[CPBV];
    #pragma unroll
    for (unsigned j = 0; j < CPBV; j++) {
        unsigned ch = c0 + j;
        unsigned k = 0u;
        if (ch < NCHUNK) {
            unsigned loc = ch * 256u + (unsigned)t - ebase;
            const float4* cp = (const float4*)(p.cls[lev]) + (size_t)loc * 4;
            float4 v0 = cp[0], v1 = cp[1], v2 = cp[2], v3 = cp[3];
            float m = fmaxf(fmaxf(max4(v0), max4(v1)), fmaxf(max4(v2), max4(v3)));
            k = f2key(m);
        }
        keys[j] = k;
    }
    // ---- Phase A2: block byte-1 hist; one flush into 1-of-16 copies ----
    hh[t] = 0u;
    __syncthreads();
    #pragma unroll
    for (unsigned j = 0; j < CPBV; j++)
        if (c0 + j < NCHUNK) atomicAdd(&hh[keys[j] >> 24], 1u);
    __syncthreads();
    {
        unsigned v = hh[t];
        if (v) atomicAdd(&histA[(b & (HP - 1u)) * HISTSZ
                                + (unsigned)lev * 256u + (unsigned)t], v);
    }
    gridbar<NBV>(bar0, wsh);

    // ---- Select byte-1 for OWN level only (LLC loads; level-pure) ----
    unsigned cA = 0;
    #pragma unroll
    for (unsigned pp = 0; pp < HP; pp++)
        cA += g_load(histA + pp * HISTSZ + (unsigned)lev * 256u + (unsigned)t);
    sel256(cA, TOPKK, wsum, aux);
    unsigned binA = aux[0], remA = aux[1];
    __syncthreads();

    // ---- Phase C: byte-2 hist of keys matching byte-1 prefix ----
    hh[t] = 0u;
    __syncthreads();
    #pragma unroll
    for (unsigned j = 0; j < CPBV; j++) {
        unsigned k = keys[j];
        if ((c0 + j) < NCHUNK && (k >> 24) == binA)
            atomicAdd(&hh[(k >> 16) & 0xFFu], 1u);
    }
    __syncthreads();
    {
        unsigned v = hh[t];
        if (v) atomicAdd(&histB[(b & (HP - 1u)) * HISTSZ
                                + (unsigned)lev * 256u + (unsigned)t], v);
    }
    gridbar<NBV>(bar1, wsh);

    // ---- Select byte-2 -> 16-bit threshold (identical semantics) ----
    unsigned cB = 0;
    #pragma unroll
    for (unsigned pp = 0; pp < HP; pp++)
        cB += g_load(histB + pp * HISTSZ + (unsigned)lev * 256u + (unsigned)t);
    sel256(cB, remA, wsum, aux);
    unsigned thresh = (binA << 24) | (aux[0] << 16);
    __syncthreads();

    // ---- Phase E: compact candidates (all stores LLC-scope) ----
    #pragma unroll
    for (unsigned j = 0; j < CPBV; j++) {
        unsigned ch = c0 + j;
        unsigned k = keys[j];
        if (ch < NCHUNK && k >= thresh) {
            unsigned loc = ch * 256u + (unsigned)t - ebase;
            unsigned part = ch & (NPART - 1u);
            unsigned slot = atomicAdd(&cnt[(lev * NPART + part) * 16u], 1u);
            if (slot < PART_CAP)
                g_store64(&cand[((size_t)(lev * NPART + part)) * PART_CAP + slot],
                          ((unsigned long long)k << 32) | (unsigned)(~loc));
        }
    }

    // ---- Exit-flag: everyone arrives; only rank blocks (0..39) wait ----
    bool ranker = b < (unsigned)(NLEV * 8);
    __syncthreads();                       // drains vmcnt (cand stores done)
    bar_arrive(bar2);
    if (b == 0) {
        bar_monitor_fanout<NBV>(bar2, wsh);
    } else if (ranker) {
        if (t == 0) bar_waitgo(bar2);
    } else {
        return;
    }
    __syncthreads();

    // ---- Phase F: rank-by-counting + emit (verified round-0 logic) ----
    const float MAXD = 4.135166556742356f;   // log(1000/16)
    int l = (int)(b >> 3);
    unsigned sl = b & 7u;

    if (t < NPART) {
        unsigned cc = g_load(cnt + (l * NPART + t) * 16u);
        aux[t] = (cc > PART_CAP) ? PART_CAP : cc;
    }
    __syncthreads();
    if (t == 0) {
        unsigned o = 0;
        for (int pp = 0; pp < NPART; pp++) { aux[16 + pp] = o; o += aux[pp]; }
        aux[32] = (o > CAND_TOT) ? CAND_TOT : o;
    }
    __syncthreads();
    unsigned n = aux[32];
    for (int pp = 0; pp < NPART; pp++) {
        unsigned cc = aux[pp], o = aux[16 + pp];
        for (unsigned e = (unsigned)t; e < cc; e += 256u) {
            unsigned dst = o + e;
            if (dst < CAND_TOT)
                lbuf[dst] = g_load64(&cand[((size_t)(l * NPART + pp)) * PART_CAP + e]);
        }
    }
    __syncthreads();

    unsigned j = sl * 256u + (unsigned)t;
    if (j >= n) return;
    unsigned long long my = lbuf[j];
    unsigned rank = 0;
    #pragma unroll 8
    for (unsigned q = 0; q < n; q++) rank += (lbuf[q] > my) ? 1u : 0u;
    if (rank >= TOPKK) return;

    unsigned idx = ~((unsigned)(my & 0xFFFFFFFFull));
    float4 an = ((const float4*)p.anc[l])[idx];
    float4 dd = ((const float4*)p.reg[l])[(size_t)idx * 2];
    float w = an.z - an.x, h = an.w - an.y;
    float cx = an.x + 0.5f * w, cy = an.y + 0.5f * h;
    float pcx = cx + dd.x * w, pcy = cy + dd.y * h;
    float pw = w * expf(fminf(dd.z, MAXD));
    float ph = h * expf(fminf(dd.w, MAXD));
    float bx = pcx - 0.5f * pw, by = pcy - 0.5f * ph;
    float bz = pcx + 0.5f * pw, bw = pcy + 0.5f * ph;

    const float4* cp = (const float4*)(p.cls[l]) + (size_t)idx * 4;
    float sg[16];
    #pragma unroll
    for (int g = 0; g < 4; g++) {
        float4 v = cp[g];
        sg[4 * g + 0] = 1.0f / (1.0f + expf(-v.x));
        sg[4 * g + 1] = 1.0f / (1.0f + expf(-v.y));
        sg[4 * g + 2] = 1.0f / (1.0f + expf(-v.z));
        sg[4 * g + 3] = 1.0f / (1.0f + expf(-v.w));
    }
    // 16 rows of [bx,by,bz,bw,score,tag] == 24 float4s, 384B contiguous
    float4* q = (float4*)(out + (size_t)(l * TOPKK + rank) * (NCLS * 6));
    #pragma unroll
    for (int g = 0; g < 8; g++) {
        float ta = (float)(2 * g + 1), tb = (float)(2 * g + 2);
        q[3 * g + 0] = make_float4(bx, by, bz, bw);
        q[3 * g + 1] = make_float4(sg[2 * g], ta, bx, by);
        q[3 * g + 2] = make_float4(bz, bw, sg[2 * g + 1], tb);
    }
}

extern "C" void kernel_launch(void* const* d_in, const int* in_sizes, int n_in,
                              void* d_out, int out_size, void* d_ws, size_t ws_size,
                              hipStream_t stream) {
    (void)in_sizes; (void)n_in; (void)out_size; (void)ws_size;
    Ptrs p;
    for (int l = 0; l < NLEV; l++) {
        p.anc[l] = (const float*)d_in[3 * l + 0];
        p.cls[l] = (const float*)d_in[3 * l + 1];
        p.reg[l] = (const float*)d_in[3 * l + 2];
    }

    // Pick the 1023-block (4/CU) variant only if the runtime occupancy
    // calculator guarantees >= 4 blocks/CU residency; else the r7-verified
    // 512-block shape. Host-side query, cached -> graph-capture safe.
    static int s_which = -1;
    if (s_which < 0) {
        int bpcu = 0;
        if (hipOccupancyMaxActiveBlocksPerMultiprocessor(
                &bpcu, (const void*)k_fused<3u, 1023u>, 256, 0) != hipSuccess)
            bpcu = 0;
        int dev = 0, ncu = 0;
        (void)hipGetDevice(&dev);
        if (hipDeviceGetAttribute(&ncu, hipDeviceAttributeMultiprocessorCount,
                                  dev) != hipSuccess || ncu < 1)
            ncu = 0;
        s_which = (bpcu >= 4 && (long long)bpcu * ncu >= 1023) ? 1 : 0;
    }

    char* w = (char*)d_ws;
    // layout (bytes):
    //   histA : 0      .. 81920   \   16 copies x 5120 B
    //   histB : 81920  .. 163840   }  one contiguous memset (193536 B)
    //   cnt   : 163840 .. 168960   }  80 counters x 64 B (1 line each)
    //   bar   : 168960 .. 193536  /   3 one-shot sets x 8192 B
    //   cand  : 193536 .. 357376      (guarded by cnt, no memset)
    unsigned* histA = (unsigned*)w;
    unsigned* histB = (unsigned*)(w + 81920);
    unsigned* cnt   = (unsigned*)(w + 163840);
    unsigned* bar   = (unsigned*)(w + 168960);
    unsigned long long* cand = (unsigned long long*)(w + 193536);
    float* out = (float*)d_out;

    (void)hipMemsetAsync(w, 0, 193536, stream);
    if (s_which == 1) {
        k_fused<3u, 1023u><<<dim3(1023), dim3(256), 0, stream>>>(
            p, histA, histB, cnt, bar, cand, out);
    } else {
        k_fused<6u, 512u><<<dim3(512), dim3(256), 0, stream>>>(
            p, histA, histB, cnt, bar, cand, out);
    }
}